// Round 6
// baseline (238.783 us; speedup 1.0000x reference)
//
#include <hip/hip_runtime.h>

#define N_NODES  100000
#define N_EDGES  3200000
#define NB       8                 // buckets
#define BN       12544             // nodes per bucket (8*12544 >= 100000)
#define SUBS     96                // slices (blocks per bucket)
#define GRID     (NB * SUBS)       // 768 blocks
#define THR      512
#define SLICE    33336             // edges per slice (div by 4; 96*33336 >= E)
#define CAP_BLK  5120              // per-block packed-edge capacity (mean 4181)
#define CAP_B    440000            // per-bucket CSR capacity (mean ~401K)

// ---- K1: per-slice in-bucket compaction + u16 degree-count partials ---------
__global__ __launch_bounds__(THR, 6) void k_degpart(
        const int* __restrict__ src, const int* __restrict__ dstp,
        unsigned* __restrict__ cnt, unsigned* __restrict__ pedge,
        unsigned short* __restrict__ cnt16) {
    __shared__ unsigned facc[BN];
    __shared__ unsigned cur;
    const int tid = threadIdx.x, lane = tid & 63;
    const int bu = blockIdx.x / SUBS, sub = blockIdx.x % SUBS;
    for (int i = tid; i < BN; i += THR) facc[i] = 0u;
    if (tid == 0) cur = 0;
    __syncthreads();

    const unsigned base_node = (unsigned)bu * BN;
    unsigned* reg = pedge + (size_t)blockIdx.x * CAP_BLK;
    const uint4* s4 = (const uint4*)src;
    const uint4* d4 = (const uint4*)dstp;
    const int e0 = sub * SLICE;
    const int qbeg = e0 >> 2;
    const int qlim = (e0 + SLICE < N_EDGES ? e0 + SLICE : N_EDGES) >> 2;

    for (int q = qbeg + tid; q < qlim; q += THR) {
        const uint4 dv = d4[q], sv = s4[q];
        const unsigned dd[4] = { dv.x, dv.y, dv.z, dv.w };
        const unsigned ss[4] = { sv.x, sv.y, sv.z, sv.w };
        #pragma unroll
        for (int k = 0; k < 4; ++k) {
            const unsigned d = dd[k];
            const unsigned dl = d - base_node;
            const bool in = (d / BN) == (unsigned)bu;
            if (in) atomicAdd(&facc[dl], 1u);
            const unsigned long long m = __ballot(in);
            const unsigned pos = (unsigned)__popcll(m & ((1ull << lane) - 1ull));
            unsigned b0 = 0;
            if (lane == 0) b0 = atomicAdd(&cur, (unsigned)__popcll(m));
            b0 = __shfl(b0, 0, 64);
            if (in) {
                const unsigned slot = b0 + pos;
                if (slot < CAP_BLK) reg[slot] = ss[k] | (dl << 17);
            }
        }
    }
    __syncthreads();
    if (tid == 0) cnt[blockIdx.x] = cur < CAP_BLK ? cur : CAP_BLK;
    unsigned short* po = cnt16 + (size_t)blockIdx.x * BN;
    for (int i = tid; i < BN; i += THR) po[i] = (unsigned short)facc[i];
}

// ---- red1x: deg/dinv/xs + in-place exclusive slice-prefix over cnt16 --------
__global__ __launch_bounds__(THR) void k_red1x(const float* __restrict__ x,
        unsigned short* __restrict__ cnt16, unsigned* __restrict__ deg,
        float* __restrict__ dinv, float* __restrict__ xs) {
    const int g = blockIdx.x * THR + threadIdx.x;
    if (g >= N_NODES) return;
    const int bu = g / BN, l = g - bu * BN;
    unsigned short* pp = cnt16 + (size_t)(bu * SUBS) * BN + l;
    unsigned run = 0;
    #pragma unroll 8
    for (int s = 0; s < SUBS; ++s) {
        const unsigned c = pp[(size_t)s * BN];
        pp[(size_t)s * BN] = (unsigned short)run;   // exclusive slice prefix
        run += c;
    }
    deg[g] = run;
    const float di = rsqrtf((float)run + 1.f);      // + self loop
    dinv[g] = di;
    xs[g] = x[g] * di;
}

// ---- per-bucket exclusive prefix over deg -> nodeOff (bucket-local), absOff -
__global__ __launch_bounds__(1024) void k_prefix(const unsigned* __restrict__ deg,
        unsigned* __restrict__ nodeOff, unsigned* __restrict__ absOff) {
    __shared__ unsigned wtot[16];
    __shared__ unsigned ctot, carry;
    const int bu = blockIdx.x;
    const int tid = threadIdx.x, wave = tid >> 6, lane = tid & 63;
    if (tid == 0) carry = 0;
    __syncthreads();
    for (int c = 0; c < 13; ++c) {                   // 13*1024 >= BN
        const int l = c * 1024 + tid;
        const int g = bu * BN + l;
        unsigned v = (l < BN && g < N_NODES) ? deg[g] : 0u;
        unsigned ps = v;
        #pragma unroll
        for (int d = 1; d < 64; d <<= 1) {
            unsigned o = __shfl_up(ps, d, 64);
            if (lane >= d) ps += o;
        }
        if (lane == 63) wtot[wave] = ps;
        __syncthreads();
        if (tid == 0) {
            unsigned run = 0;
            #pragma unroll
            for (int w = 0; w < 16; ++w) { unsigned t = wtot[w]; wtot[w] = run; run += t; }
            ctot = run;
        }
        __syncthreads();
        const unsigned excl = carry + wtot[wave] + (ps - v);
        if (l < BN) {
            nodeOff[bu * BN + l] = excl;
            if (g < N_NODES) absOff[g] = (unsigned)bu * CAP_B + excl;
        }
        __syncthreads();
        if (tid == 0) carry += ctot;
        __syncthreads();
    }
}

// ---- placement: scatter src ids into CSR slots via LDS cursors --------------
__global__ __launch_bounds__(THR, 3) void k_place(
        const unsigned* __restrict__ pedge, const unsigned* __restrict__ cnt,
        const unsigned short* __restrict__ cnt16, const unsigned* __restrict__ nodeOff,
        unsigned* __restrict__ csr) {
    __shared__ unsigned curs[BN];
    const int tid = threadIdx.x;
    const int r = blockIdx.x;
    const int bu = r / SUBS;
    const unsigned short* sp = cnt16 + (size_t)r * BN;
    const unsigned* no = nodeOff + bu * BN;
    for (int i = tid; i < BN; i += THR) curs[i] = no[i] + (unsigned)sp[i];
    __syncthreads();
    const unsigned n = cnt[r];
    const unsigned* reg = pedge + (size_t)r * CAP_BLK;
    unsigned* cb = csr + (size_t)bu * CAP_B;
    for (unsigned j = tid; j < n; j += THR) {
        const unsigned w = reg[j];
        const unsigned slot = atomicAdd(&curs[w >> 17], 1u);
        cb[slot] = w & 0x1FFFFu;                     // global src id
    }
}

// ---- segmented pass 2: aggregate xs -> us, uself ----------------------------
__global__ __launch_bounds__(THR) void k_seg2(const float* __restrict__ x,
        const float* __restrict__ xs, const unsigned* __restrict__ csr,
        const unsigned* __restrict__ absOff, const unsigned* __restrict__ deg,
        const float* __restrict__ dinv,
        const float* __restrict__ W1, const float* __restrict__ b1,
        const float* __restrict__ W2, const float* __restrict__ Wl,
        float* __restrict__ us, float* __restrict__ uself) {
    const int g = blockIdx.x * THR + threadIdx.x;
    if (g >= N_NODES) return;
    const unsigned o = absOff[g], d = deg[g];
    float sum = 0.f;
    for (unsigned k = 0; k < d; ++k) sum += xs[csr[o + k]];
    const float di = dinv[g];
    const float s1 = di * sum + x[g] * di * di;
    float u = 0.f;
    #pragma unroll
    for (int c = 0; c < 16; ++c) {
        float vcc = 0.f;
        #pragma unroll
        for (int k = 0; k < 16; ++k) vcc += W2[c * 16 + k] * Wl[k];   // (W2@Wl)[c]
        u += fmaxf(W1[c] * s1 + b1[c], 0.f) * vcc;
    }
    us[g] = u * di;
    uself[g] = u * di * di;
}

// ---- segmented pass 3: aggregate us -> output -------------------------------
__global__ __launch_bounds__(THR) void k_seg3(const unsigned* __restrict__ csr,
        const unsigned* __restrict__ absOff, const unsigned* __restrict__ deg,
        const float* __restrict__ us, const float* __restrict__ dinv,
        const float* __restrict__ uself,
        const float* __restrict__ W2, const float* __restrict__ b2,
        const float* __restrict__ Wl, const float* __restrict__ bl,
        float* __restrict__ out) {
    const int g = blockIdx.x * THR + threadIdx.x;
    if (g >= N_NODES) return;
    const unsigned o = absOff[g], d = deg[g];
    float sum = 0.f;
    for (unsigned k = 0; k < d; ++k) sum += us[csr[o + k]];
    float vcb = bl[0];
    #pragma unroll
    for (int c = 0; c < 16; ++c) {
        float vcc = 0.f;
        #pragma unroll
        for (int k = 0; k < 16; ++k) vcc += W2[c * 16 + k] * Wl[k];
        vcb += b2[c] * vcc;
    }
    out[g] = dinv[g] * sum + uself[g] + vcb;
}

extern "C" void kernel_launch(void* const* d_in, const int* in_sizes, int n_in,
                              void* d_out, int out_size, void* d_ws, size_t ws_size,
                              hipStream_t stream) {
    const float* x  = (const float*)d_in[0];
    const int*   ei = (const int*)d_in[1];
    const float* W1 = (const float*)d_in[2];
    const float* b1 = (const float*)d_in[3];
    const float* W2 = (const float*)d_in[4];
    const float* b2 = (const float*)d_in[5];
    const float* Wl = (const float*)d_in[6];
    const float* bl = (const float*)d_in[7];
    float* out = (float*)d_out;

    const int* src  = ei;
    const int* dstp = ei + N_EDGES;

    unsigned* cnt         = (unsigned*)d_ws;
    unsigned* pedge       = cnt + 1024;
    unsigned short* cnt16 = (unsigned short*)(pedge + (size_t)GRID * CAP_BLK);
    unsigned* nodeOff     = (unsigned*)(cnt16 + (size_t)GRID * BN);
    unsigned* absOff      = nodeOff + NB * BN;
    unsigned* deg         = absOff + N_NODES;
    float*    dinv        = (float*)(deg + N_NODES);
    float*    xs          = dinv + N_NODES;
    float*    us          = xs + N_NODES;
    float*    uself       = us + N_NODES;
    unsigned* csr         = (unsigned*)(uself + N_NODES);

    const int red_blocks = (N_NODES + THR - 1) / THR;   // 196

    k_degpart<<<GRID, THR, 0, stream>>>(src, dstp, cnt, pedge, cnt16);
    k_red1x<<<red_blocks, THR, 0, stream>>>(x, cnt16, deg, dinv, xs);
    k_prefix<<<NB, 1024, 0, stream>>>(deg, nodeOff, absOff);
    k_place<<<GRID, THR, 0, stream>>>(pedge, cnt, cnt16, nodeOff, csr);
    k_seg2<<<red_blocks, THR, 0, stream>>>(x, xs, csr, absOff, deg, dinv,
                                           W1, b1, W2, Wl, us, uself);
    k_seg3<<<red_blocks, THR, 0, stream>>>(csr, absOff, deg, us, dinv, uself,
                                           W2, b2, Wl, bl, out);
}

// Round 7
// 172.575 us; speedup vs baseline: 1.3836x; 1.3836x over previous
//
#include <hip/hip_runtime.h>

#define N_NODES  100000
#define N_EDGES  3200000
#define NB       8                 // buckets
#define BN       12544             // nodes per bucket (8*12544 >= 100000)
#define S1       96                // K1 slices per bucket
#define G1       (NB * S1)         // 768 K1 blocks
#define SA       32                // acc slices per bucket
#define GA       (NB * SA)         // 256 acc blocks
#define RPB      (S1 / SA)         // 3 pedge regions per acc block
#define THR      512
#define THRA     1024
#define SLICE    33336             // edges per K1 slice (div by 4; 96*33336 >= E)
#define CAP_BLK  5120              // per-region packed-edge capacity (mean 4167)

// ws layout (4-byte words):
//  cnt[1024] | pedge[G1*CAP_BLK] | cnt16 (u16, G1*BN) | partials f32[GA*BN]
//  | dinv[N] | xs[N] | us[N] | uself[N]

// ---- K1: per-slice in-bucket compaction + u16 degree-count partials ---------
__global__ __launch_bounds__(THR, 6) void k_degpart(
        const int* __restrict__ src, const int* __restrict__ dstp,
        unsigned* __restrict__ cnt, unsigned* __restrict__ pedge,
        unsigned short* __restrict__ cnt16) {
    __shared__ unsigned facc[BN];
    __shared__ unsigned cur;
    const int tid = threadIdx.x, lane = tid & 63;
    const int bu = blockIdx.x / S1, sub = blockIdx.x % S1;
    for (int i = tid; i < BN; i += THR) facc[i] = 0u;
    if (tid == 0) cur = 0;
    __syncthreads();

    const unsigned base_node = (unsigned)bu * BN;
    unsigned* reg = pedge + (size_t)blockIdx.x * CAP_BLK;
    const uint4* s4 = (const uint4*)src;
    const uint4* d4 = (const uint4*)dstp;
    const int e0 = sub * SLICE;
    const int qbeg = e0 >> 2;
    const int qlim = (e0 + SLICE < N_EDGES ? e0 + SLICE : N_EDGES) >> 2;

    for (int q = qbeg + tid; q < qlim; q += THR) {
        const uint4 dv = d4[q], sv = s4[q];
        const unsigned dd[4] = { dv.x, dv.y, dv.z, dv.w };
        const unsigned ss[4] = { sv.x, sv.y, sv.z, sv.w };
        #pragma unroll
        for (int k = 0; k < 4; ++k) {
            const unsigned d = dd[k];
            const unsigned dl = d - base_node;
            const bool in = (d / BN) == (unsigned)bu;
            if (in) atomicAdd(&facc[dl], 1u);
            const unsigned long long m = __ballot(in);
            const unsigned pos = (unsigned)__popcll(m & ((1ull << lane) - 1ull));
            unsigned b0 = 0;
            if (lane == 0) b0 = atomicAdd(&cur, (unsigned)__popcll(m));
            b0 = __shfl(b0, 0, 64);
            if (in) {
                const unsigned slot = b0 + pos;
                if (slot < CAP_BLK) reg[slot] = ss[k] | (dl << 17);
            }
        }
    }
    __syncthreads();
    if (tid == 0) cnt[blockIdx.x] = cur < CAP_BLK ? cur : CAP_BLK;
    unsigned short* po = cnt16 + (size_t)blockIdx.x * BN;
    for (int i = tid; i < BN; i += THR) po[i] = (unsigned short)facc[i];
}

// ---- red1: sum u16 degree partials -> dinv, xs ------------------------------
__global__ __launch_bounds__(THR) void k_red1(const float* __restrict__ x,
        const unsigned short* __restrict__ cnt16,
        float* __restrict__ dinv, float* __restrict__ xs) {
    const int g = blockIdx.x * THR + threadIdx.x;
    if (g >= N_NODES) return;
    const int bu = g / BN, l = g - bu * BN;
    const unsigned short* pp = cnt16 + (size_t)(bu * S1) * BN + l;
    unsigned run = 0;
    #pragma unroll 8
    for (int s = 0; s < S1; ++s) run += pp[(size_t)s * BN];
    const float di = rsqrtf((float)run + 1.f);      // + self loop
    dinv[g] = di;
    xs[g] = x[g] * di;
}

// ---- acc: scatter vals[src] into LDS bucket image from 3 pedge regions ------
__global__ __launch_bounds__(THRA) void k_acc(
        const unsigned* __restrict__ pedge, const unsigned* __restrict__ cnt,
        const float* __restrict__ vals, float* __restrict__ partials) {
    __shared__ float facc[BN];
    const int tid = threadIdx.x;
    const int bu = blockIdx.x / SA, sub = blockIdx.x % SA;
    for (int i = tid; i < BN; i += THRA) facc[i] = 0.f;
    __syncthreads();
    #pragma unroll
    for (int r3 = 0; r3 < RPB; ++r3) {
        const int r = bu * S1 + sub * RPB + r3;
        const unsigned n = cnt[r];
        const unsigned* reg = pedge + (size_t)r * CAP_BLK;
        for (unsigned j = tid; j < n; j += THRA) {
            const unsigned w = reg[j];
            atomicAdd(&facc[w >> 17], vals[w & 0x1FFFFu]);
        }
    }
    __syncthreads();
    float* po = partials + (size_t)blockIdx.x * BN;
    for (int i = tid; i < BN; i += THRA) po[i] = facc[i];
}

// ---- partial reduction helper (SA slices) -----------------------------------
__device__ __forceinline__ float sum_partials(const float* __restrict__ partials,
                                              int g) {
    const int bu = g / BN, l = g - bu * BN;
    const float* pp = partials + (size_t)(bu * SA) * BN + l;
    float s = 0.f;
    #pragma unroll
    for (int k = 0; k < SA; ++k) s += pp[(size_t)k * BN];
    return s;
}

__global__ __launch_bounds__(THR) void k_red2(const float* __restrict__ x,
        const float* __restrict__ partials, const float* __restrict__ dinv,
        const float* __restrict__ W1, const float* __restrict__ b1,
        const float* __restrict__ W2, const float* __restrict__ Wl,
        float* __restrict__ us, float* __restrict__ uself) {
    const int g = blockIdx.x * THR + threadIdx.x;
    if (g >= N_NODES) return;
    const float sum = sum_partials(partials, g);
    const float di = dinv[g];
    const float s1 = di * sum + x[g] * di * di;
    float u = 0.f;
    #pragma unroll
    for (int c = 0; c < 16; ++c) {
        float vcc = 0.f;
        #pragma unroll
        for (int k = 0; k < 16; ++k) vcc += W2[c * 16 + k] * Wl[k];  // (W2@Wl)[c]
        u += fmaxf(W1[c] * s1 + b1[c], 0.f) * vcc;
    }
    us[g] = u * di;
    uself[g] = u * di * di;
}

__global__ __launch_bounds__(THR) void k_red3(const float* __restrict__ partials,
        const float* __restrict__ dinv, const float* __restrict__ uself,
        const float* __restrict__ W2, const float* __restrict__ b2,
        const float* __restrict__ Wl, const float* __restrict__ bl,
        float* __restrict__ out) {
    const int g = blockIdx.x * THR + threadIdx.x;
    if (g >= N_NODES) return;
    const float sum = sum_partials(partials, g);
    float vcb = bl[0];
    #pragma unroll
    for (int c = 0; c < 16; ++c) {
        float vcc = 0.f;
        #pragma unroll
        for (int k = 0; k < 16; ++k) vcc += W2[c * 16 + k] * Wl[k];
        vcb += b2[c] * vcc;
    }
    out[g] = dinv[g] * sum + uself[g] + vcb;
}

extern "C" void kernel_launch(void* const* d_in, const int* in_sizes, int n_in,
                              void* d_out, int out_size, void* d_ws, size_t ws_size,
                              hipStream_t stream) {
    const float* x  = (const float*)d_in[0];
    const int*   ei = (const int*)d_in[1];
    const float* W1 = (const float*)d_in[2];
    const float* b1 = (const float*)d_in[3];
    const float* W2 = (const float*)d_in[4];
    const float* b2 = (const float*)d_in[5];
    const float* Wl = (const float*)d_in[6];
    const float* bl = (const float*)d_in[7];
    float* out = (float*)d_out;

    const int* src  = ei;
    const int* dstp = ei + N_EDGES;

    unsigned* cnt         = (unsigned*)d_ws;
    unsigned* pedge       = cnt + 1024;
    unsigned short* cnt16 = (unsigned short*)(pedge + (size_t)G1 * CAP_BLK);
    float*    partials    = (float*)(cnt16 + (size_t)G1 * BN);
    float*    dinv        = partials + (size_t)GA * BN;
    float*    xs          = dinv + N_NODES;
    float*    us          = xs + N_NODES;
    float*    uself       = us + N_NODES;

    const int red_blocks = (N_NODES + THR - 1) / THR;   // 196

    k_degpart<<<G1, THR, 0, stream>>>(src, dstp, cnt, pedge, cnt16);
    k_red1<<<red_blocks, THR, 0, stream>>>(x, cnt16, dinv, xs);
    k_acc<<<GA, THRA, 0, stream>>>(pedge, cnt, xs, partials);
    k_red2<<<red_blocks, THR, 0, stream>>>(x, partials, dinv, W1, b1, W2, Wl, us, uself);
    k_acc<<<GA, THRA, 0, stream>>>(pedge, cnt, us, partials);
    k_red3<<<red_blocks, THR, 0, stream>>>(partials, dinv, uself, W2, b2, Wl, bl, out);
}